// Round 2
// baseline (168.042 us; speedup 1.0000x reference)
//
#include <hip/hip_runtime.h>

#define N_DOWN  50000
#define N_ABOVE 100000
#define DIM     256
#define FAN     5
#define K1      1280      // FAN * DIM
#define MPAD    100096    // 782 * 128
#define NT      20        // K1 / 64 K-tiles

typedef __bf16 bf16x8 __attribute__((ext_vector_type(8)));
typedef float  f32x4  __attribute__((ext_vector_type(4)));

__device__ __forceinline__ unsigned short f2bf(float f) {
  unsigned u = __builtin_bit_cast(unsigned, f);
  u += 0x7FFFu + ((u >> 16) & 1u);          // RNE round to bf16
  return (unsigned short)(u >> 16);
}

__device__ __forceinline__ void gload16(const unsigned short* g, unsigned short* l) {
  __builtin_amdgcn_global_load_lds(
      (const __attribute__((address_space(1))) void*)g,
      (__attribute__((address_space(3))) void*)l, 16, 0, 0);
}

#define BAR()   __builtin_amdgcn_s_barrier()
#define LGKM0() do { asm volatile("s_waitcnt lgkmcnt(0)" ::: "memory"); \
                     __builtin_amdgcn_sched_barrier(0); } while (0)

// ---- prep ----
__global__ void k_prep_inv(int* __restrict__ inv, unsigned short* __restrict__ hbf) {
  int t = blockIdx.x * 256 + threadIdx.x;
  if (t < N_ABOVE) inv[t] = N_DOWN;                 // sentinel -> zero row
  if (t < DIM)     hbf[(size_t)N_DOWN * DIM + t] = 0;
}

__global__ void k_scatter(const int* __restrict__ idx, int* __restrict__ inv) {
  int t = blockIdx.x * 256 + threadIdx.x;
  if (t < N_DOWN) inv[idx[t]] = t;
}

__global__ void k_h2bf(const float* __restrict__ h, unsigned short* __restrict__ hbf) {
  int t = blockIdx.x * 256 + threadIdx.x;           // grid sized exactly: 12500*256
  float4 v = ((const float4*)h)[t];
  ushort4 o;
  o.x = f2bf(v.x); o.y = f2bf(v.y); o.z = f2bf(v.z); o.w = f2bf(v.w);
  ((ushort4*)hbf)[t] = o;
}

// in: [K][N] f32 row-major -> out: [N][K] bf16 row-major
__global__ void k_transpose_bf(const float* __restrict__ in, unsigned short* __restrict__ out,
                               int K, int N) {
  __shared__ float tile[64][65];
  int k0 = blockIdx.x * 64, n0 = blockIdx.y * 64;
  int c = threadIdx.x & 63, rb = threadIdx.x >> 6;
#pragma unroll
  for (int rr = 0; rr < 16; ++rr) {
    int row = rb + rr * 4;
    tile[row][c] = in[(size_t)(k0 + row) * N + n0 + c];
  }
  __syncthreads();
#pragma unroll
  for (int rr = 0; rr < 16; ++rr) {
    int nr = rb + rr * 4;
    out[(size_t)(n0 + nr) * K + k0 + c] = f2bf(tile[c][nr]);
  }
}

// ---- GEMM1 (phased, counted-vmcnt): hid = relu(gather(hbf) @ W1 + b1) ----
// BM=128, BN=256 (full N), BK=64, 512 thr = 8 waves (2M x 4N), ring-3 LDS.
__global__ __launch_bounds__(512, 2) void k_gemm1(
    const unsigned short* __restrict__ hbf,   // [N_DOWN+1][256] bf16
    const unsigned short* __restrict__ w1t,   // [256][1280]  bf16 (W1^T)
    const float* __restrict__ b1,
    const int* __restrict__ inv,              // [N_ABOVE]
    const int* __restrict__ jarr,             // [N_ABOVE*FAN]
    unsigned short* __restrict__ hid)         // [MPAD][256] bf16
{
  extern __shared__ __align__(16) unsigned short smem[];
  unsigned short* As = smem;                  // 3 * 128*64
  unsigned short* Bs = smem + 3 * 128 * 64;   // 3 * 256*64

  const int tid = threadIdx.x;
  const int w = tid >> 6, l = tid & 63;
  const int m0 = blockIdx.x * 128;
  const int wm = w & 1, wn = w >> 1;          // 2M x 4N wave grid
  const int la = l >> 3, lc = l & 7;

  // stage-A rows owned by this thread (2 loads/tile), swizzled source chunk
  const int rA0 = w * 16 + la;
  const int rA1 = w * 16 + 8 + la;
  const int cA0 = lc ^ (rA0 & 7);
  const int cA1 = lc ^ (rA1 & 7);
  // stage-B rows (4 loads/tile)
  const int rB0 = w * 32 + la,      cB0 = lc ^ (rB0 & 7);
  const int rB1 = w * 32 + 8 + la,  cB1 = lc ^ (rB1 & 7);
  const int rB2 = w * 32 + 16 + la, cB2 = lc ^ (rB2 & 7);
  const int rB3 = w * 32 + 24 + la, cB3 = lc ^ (rB3 & 7);

  // gather sources for my two A-rows, all 5 segments (named regs, static)
  const int gm0 = min(m0 + rA0, N_ABOVE - 1);
  const int gm1 = min(m0 + rA1, N_ABOVE - 1);
  const int s00 = inv[jarr[gm0 * FAN + 0]], s01 = inv[jarr[gm0 * FAN + 1]],
            s02 = inv[jarr[gm0 * FAN + 2]], s03 = inv[jarr[gm0 * FAN + 3]],
            s04 = inv[jarr[gm0 * FAN + 4]];
  const int s10 = inv[jarr[gm1 * FAN + 0]], s11 = inv[jarr[gm1 * FAN + 1]],
            s12 = inv[jarr[gm1 * FAN + 2]], s13 = inv[jarr[gm1 * FAN + 3]],
            s14 = inv[jarr[gm1 * FAN + 4]];
  // clean VMEM FIFO before staged loads begin
  asm volatile("s_waitcnt vmcnt(0)" ::: "memory");
  __builtin_amdgcn_sched_barrier(0);

  // prologue: stage tiles 0 and 1 (6 loads each)
#pragma unroll
  for (int t = 0; t < 2; ++t) {
    unsigned short* An = As + t * (128 * 64);
    unsigned short* Bn = Bs + t * (256 * 64);
    int u = t >> 2;                            // = 0
    (void)u;
    int a0 = (t == 0) ? s00 : s00;             // segment 0 for t=0,1
    int a1 = (t == 0) ? s10 : s10;
    gload16(hbf + ((size_t)a0 << 8) + ((t & 3) << 6) + (cA0 << 3), An + (w * 2 + 0) * 512);
    gload16(hbf + ((size_t)a1 << 8) + ((t & 3) << 6) + (cA1 << 3), An + (w * 2 + 1) * 512);
    gload16(w1t + (size_t)rB0 * K1 + (t << 6) + (cB0 << 3), Bn + (w * 4 + 0) * 512);
    gload16(w1t + (size_t)rB1 * K1 + (t << 6) + (cB1 << 3), Bn + (w * 4 + 1) * 512);
    gload16(w1t + (size_t)rB2 * K1 + (t << 6) + (cB2 << 3), Bn + (w * 4 + 2) * 512);
    gload16(w1t + (size_t)rB3 * K1 + (t << 6) + (cB3 << 3), Bn + (w * 4 + 3) * 512);
  }
  asm volatile("s_waitcnt vmcnt(6)" ::: "memory");   // tile 0 landed
  BAR();

  f32x4 acc[4][4] = {};
  int cur = 0;

  for (int t = 0; t < NT; ++t) {
    const int t2 = t + 2;
    const bool do_stage = (t2 < NT);
    const int u = t2 >> 2;
    const int sA0 = u == 0 ? s00 : u == 1 ? s01 : u == 2 ? s02 : u == 3 ? s03 : s04;
    const int sA1 = u == 0 ? s10 : u == 1 ? s11 : u == 2 ? s12 : u == 3 ? s13 : s14;
    unsigned short* Ab = As + cur * (128 * 64);
    unsigned short* Bb = Bs + cur * (256 * 64);
    int nx = cur + 2; if (nx >= 3) nx -= 3;
    unsigned short* An = As + nx * (128 * 64);
    unsigned short* Bn = Bs + nx * (256 * 64);

    // ================= phase A (kk=0) =================
    bf16x8 a0[4], b0[4];
#pragma unroll
    for (int mf = 0; mf < 4; ++mf) {
      int row = wm * 64 + mf * 16 + (l & 15);
      int p = (l >> 4) ^ (row & 7);
      a0[mf] = *(const bf16x8*)(Ab + row * 64 + p * 8);
    }
#pragma unroll
    for (int nf = 0; nf < 4; ++nf) {
      int row = wn * 64 + nf * 16 + (l & 15);
      int p = (l >> 4) ^ (row & 7);
      b0[nf] = *(const bf16x8*)(Bb + row * 64 + p * 8);
    }
    if (do_stage) {
      gload16(hbf + ((size_t)sA0 << 8) + ((t2 & 3) << 6) + (cA0 << 3), An + (w * 2 + 0) * 512);
      gload16(hbf + ((size_t)sA1 << 8) + ((t2 & 3) << 6) + (cA1 << 3), An + (w * 2 + 1) * 512);
      gload16(w1t + (size_t)rB0 * K1 + (t2 << 6) + (cB0 << 3), Bn + (w * 4 + 0) * 512);
    }
    BAR();
    LGKM0();
    __builtin_amdgcn_s_setprio(1);
#pragma unroll
    for (int mf = 0; mf < 4; ++mf)
#pragma unroll
      for (int nf = 0; nf < 4; ++nf)
        acc[mf][nf] = __builtin_amdgcn_mfma_f32_16x16x32_bf16(a0[mf], b0[nf], acc[mf][nf], 0, 0, 0);
    __builtin_amdgcn_s_setprio(0);
    BAR();

    // ================= phase B (kk=1) =================
    bf16x8 a1[4], b1f[4];
#pragma unroll
    for (int mf = 0; mf < 4; ++mf) {
      int row = wm * 64 + mf * 16 + (l & 15);
      int p = (4 + (l >> 4)) ^ (row & 7);
      a1[mf] = *(const bf16x8*)(Ab + row * 64 + p * 8);
    }
#pragma unroll
    for (int nf = 0; nf < 4; ++nf) {
      int row = wn * 64 + nf * 16 + (l & 15);
      int p = (4 + (l >> 4)) ^ (row & 7);
      b1f[nf] = *(const bf16x8*)(Bb + row * 64 + p * 8);
    }
    if (do_stage) {
      gload16(w1t + (size_t)rB1 * K1 + (t2 << 6) + (cB1 << 3), Bn + (w * 4 + 1) * 512);
      gload16(w1t + (size_t)rB2 * K1 + (t2 << 6) + (cB2 << 3), Bn + (w * 4 + 2) * 512);
      gload16(w1t + (size_t)rB3 * K1 + (t2 << 6) + (cB3 << 3), Bn + (w * 4 + 3) * 512);
    }
    BAR();
    LGKM0();
    __builtin_amdgcn_s_setprio(1);
#pragma unroll
    for (int mf = 0; mf < 4; ++mf)
#pragma unroll
      for (int nf = 0; nf < 4; ++nf)
        acc[mf][nf] = __builtin_amdgcn_mfma_f32_16x16x32_bf16(a1[mf], b1f[nf], acc[mf][nf], 0, 0, 0);
    __builtin_amdgcn_s_setprio(0);
    // counted wait: retire tile t+1's 6 loads; only the tail drains
    if (t == NT - 2) {
      asm volatile("s_waitcnt vmcnt(0)" ::: "memory");
    } else if (t < NT - 2) {
      asm volatile("s_waitcnt vmcnt(6)" ::: "memory");
    }
    BAR();

    ++cur; if (cur >= 3) cur = 0;
  }

  // epilogue: bias + relu -> bf16
#pragma unroll
  for (int nf = 0; nf < 4; ++nf) {
    int gn = wn * 64 + nf * 16 + (l & 15);
    float bias = b1[gn];
#pragma unroll
    for (int mf = 0; mf < 4; ++mf) {
      int gr0 = m0 + wm * 64 + mf * 16 + (l >> 4) * 4;
#pragma unroll
      for (int q = 0; q < 4; ++q) {
        float v = acc[mf][nf][q] + bias;
        v = v > 0.f ? v : 0.f;
        hid[(size_t)(gr0 + q) * DIM + gn] = f2bf(v);
      }
    }
  }
}

// ---- GEMM2: out = hid @ W2 + b2, f32 out [N_ABOVE][256] ----
__global__ __launch_bounds__(256, 2) void k_gemm2(
    const unsigned short* __restrict__ hid,   // [MPAD][256] bf16
    const unsigned short* __restrict__ w2t,   // [256][256] bf16 (W2^T)
    const float* __restrict__ b2,
    float* __restrict__ out)
{
  __shared__ __align__(16) unsigned short Alds[128 * 64];
  __shared__ __align__(16) unsigned short Blds[128 * 64];

  const int tid = threadIdx.x;
  const int w = tid >> 6, l = tid & 63;
  const int m0 = blockIdx.x * 128, n0 = blockIdx.y * 128;
  const int wm = w >> 1, wn = w & 1;
  const int srow = l >> 3, slot = l & 7;

  f32x4 acc[4][4] = {};

  for (int t = 0; t < 4; ++t) {
    __syncthreads();
#pragma unroll
    for (int i = 0; i < 4; ++i) {
      int row = w * 32 + i * 8 + srow;
      int c = slot ^ (row & 7);
      gload16(hid + (size_t)(m0 + row) * DIM + (t << 6) + (c << 3),
              Alds + (w * 32 + i * 8) * 64);
      gload16(w2t + (size_t)(n0 + row) * DIM + (t << 6) + (c << 3),
              Blds + (w * 32 + i * 8) * 64);
    }
    __syncthreads();

#pragma unroll
    for (int kk = 0; kk < 2; ++kk) {
      bf16x8 af[4], bfr[4];
#pragma unroll
      for (int m = 0; m < 4; ++m) {
        int row = wm * 64 + m * 16 + (l & 15);
        int c = (kk * 4 + (l >> 4)) ^ (row & 7);
        af[m] = *(const bf16x8*)(Alds + row * 64 + c * 8);
      }
#pragma unroll
      for (int n = 0; n < 4; ++n) {
        int row = wn * 64 + n * 16 + (l & 15);
        int c = (kk * 4 + (l >> 4)) ^ (row & 7);
        bfr[n] = *(const bf16x8*)(Blds + row * 64 + c * 8);
      }
#pragma unroll
      for (int m = 0; m < 4; ++m)
#pragma unroll
        for (int n = 0; n < 4; ++n)
          acc[m][n] = __builtin_amdgcn_mfma_f32_16x16x32_bf16(af[m], bfr[n], acc[m][n], 0, 0, 0);
    }
  }

#pragma unroll
  for (int n = 0; n < 4; ++n) {
    int gn = n0 + wn * 64 + n * 16 + (l & 15);
    float bias = b2[gn];
#pragma unroll
    for (int m = 0; m < 4; ++m) {
      int gm0 = m0 + wm * 64 + m * 16 + (l >> 4) * 4;
#pragma unroll
      for (int q = 0; q < 4; ++q) {
        int gm = gm0 + q;
        if (gm < N_ABOVE) out[(size_t)gm * DIM + gn] = acc[m][n][q] + bias;
      }
    }
  }
}

extern "C" void kernel_launch(void* const* d_in, const int* in_sizes, int n_in,
                              void* d_out, int out_size, void* d_ws, size_t ws_size,
                              hipStream_t stream) {
  const float* h    = (const float*)d_in[0];
  const int*   idx  = (const int*)d_in[2];
  const int*   jarr = (const int*)d_in[4];
  const float* W1   = (const float*)d_in[5];
  const float* b1   = (const float*)d_in[6];
  const float* W2   = (const float*)d_in[7];
  const float* b2   = (const float*)d_in[8];
  float* out = (float*)d_out;

  char* ws = (char*)d_ws;
  size_t off = 0;
  auto alloc = [&](size_t bytes) -> void* {
    void* p = ws + off;
    off += bytes;
    off = (off + 511) & ~(size_t)511;
    return p;
  };
  int*            inv = (int*)alloc((size_t)N_ABOVE * 4);
  unsigned short* hbf = (unsigned short*)alloc((size_t)(N_DOWN + 1) * DIM * 2);
  unsigned short* w1t = (unsigned short*)alloc((size_t)DIM * K1 * 2);
  unsigned short* w2t = (unsigned short*)alloc((size_t)DIM * DIM * 2);
  unsigned short* hid = (unsigned short*)alloc((size_t)MPAD * DIM * 2);
  if (ws_size < off) return;

  k_prep_inv<<<dim3(391), dim3(256), 0, stream>>>(inv, hbf);
  k_scatter<<<dim3(196), dim3(256), 0, stream>>>(idx, inv);
  k_h2bf<<<dim3(12500), dim3(256), 0, stream>>>(h, hbf);
  k_transpose_bf<<<dim3(K1 / 64, DIM / 64), dim3(256), 0, stream>>>(W1, w1t, K1, DIM);
  k_transpose_bf<<<dim3(DIM / 64, DIM / 64), dim3(256), 0, stream>>>(W2, w2t, DIM, DIM);
  const size_t smem1 = (size_t)(3 * 128 * 64 + 3 * 256 * 64) * sizeof(unsigned short); // 144 KiB
  k_gemm1<<<dim3(MPAD / 128), dim3(512), smem1, stream>>>(hbf, w1t, b1, inv, jarr, hid);
  k_gemm2<<<dim3(MPAD / 128, 2), dim3(256), 0, stream>>>(hid, w2t, b2, out);
}